// Round 20
// baseline (189.946 us; speedup 1.0000x reference)
//
#include <hip/hip_runtime.h>

// GCN 2-layer forward, CSR-gather formulation. All fp32.
// out[d] = dinv[d] * ( sum_{e: src->d} g[src] + g[d] ) + bias,
// where g[i] = (h W)[i] * dinv[i]; self-loop is the +g[d] term.
// CSR built via SINGLE-PASS capacity binning, 782 buckets x 128 nodes:
//   k_bin:    stage edges in regs, LDS hist+scan (4 slots/thread), one
//             global reserve per (block,bucket), LDS counting sort,
//             COALESCED write of packed (src<<7|dst&127) runs into b*CAP+...
//   k_place:  per-bucket (512 thr): bucket's edges staged in LDS once;
//             per-node counts/scan in LDS -> row_start/cnt/dinv; place csr
//             from the LDS copy.
//   k_gemm1:  g1 = (x @ W1) * dinv. W1 in LDS (o-major XOR-swizzled);
//             G1R=2 rows/wave/iter, double-buffered x prefetch, (256,2).
//             REGISTER RULE (r14/r18): requesting >2 waves/EU forces the
//             allocator below the live set -> scratch spills (FETCH 548-
//             879MB). Instead G1R=2 SHRINKS live VGPRs to ~90 so 4 waves/
//             SIMD happen naturally under the safe (256,2) cap.
//   k_gather1: CSR gather of g1, float4-vectorized (lane=eo*4+q).
//   k_gather2: CSR gather of g2, half-wave per node (deg~33); bias -> out.

#define BKT_SHIFT 7            // 128 nodes per bucket
#define BKT_MASK 127
#define BIN_EPT 16             // edges per thread in k_bin (4096/block)
#define CAP 5120               // per-bucket capacity (expected 4092, sigma~64)

// Bin packed edges (src<<7 | dst&127) into per-bucket capacity regions.
// LDS counting sort inside the block -> coalesced run writes.
// Dynamic LDS: h[NB], ls[NB], gb[NB], sorted[4096] int, bkt[4096] ushort.
__global__ __launch_bounds__(256) void k_bin(
    const int* __restrict__ src, const int* __restrict__ dst,
    int* __restrict__ bucket_cursor, int* __restrict__ binned, int E, int NB) {
    extern __shared__ int lds[];
    int* h  = lds;
    int* ls = lds + NB;
    int* gb = lds + 2 * NB;
    int* sorted = lds + 3 * NB;
    unsigned short* bkt = (unsigned short*)(sorted + 256 * BIN_EPT);
    __shared__ int ps[256];
    const int t = threadIdx.x;
    const int base = blockIdx.x * (256 * BIN_EPT);
    const int count = min(256 * BIN_EPT, E - base);  // valid edges this block

    for (int b = t; b < NB; b += 256) h[b] = 0;
    __syncthreads();
    // Stage edges in registers + local histogram.
    int s_[BIN_EPT], d_[BIN_EPT];
#pragma unroll
    for (int j = 0; j < BIN_EPT; ++j) {
        int e = base + j * 256 + t;
        if (e < E) {
            s_[j] = src[e];
            d_[j] = dst[e];
            atomicAdd(&h[d_[j] >> BKT_SHIFT], 1);
        }
    }
    __syncthreads();
    // Block scan of h (4 slots per thread): serial partial + 256-scan.
    {
        int v0 = 0, v1 = 0, v2 = 0, v3 = 0;
        int i0 = 4 * t;
        if (i0 + 0 < NB) v0 = h[i0 + 0];
        if (i0 + 1 < NB) v1 = h[i0 + 1];
        if (i0 + 2 < NB) v2 = h[i0 + 2];
        if (i0 + 3 < NB) v3 = h[i0 + 3];
        int tot = v0 + v1 + v2 + v3;
        ps[t] = tot;
        __syncthreads();
        for (int off = 1; off < 256; off <<= 1) {
            int u = (t >= off) ? ps[t - off] : 0;
            __syncthreads();
            ps[t] += u;
            __syncthreads();
        }
        int excl = ps[t] - tot;
        if (i0 + 0 < NB) { ls[i0 + 0] = excl; excl += v0; }
        if (i0 + 1 < NB) { ls[i0 + 1] = excl; excl += v1; }
        if (i0 + 2 < NB) { ls[i0 + 2] = excl; excl += v2; }
        if (i0 + 3 < NB) { ls[i0 + 3] = excl; }
    }
    __syncthreads();
    // Reserve capacity-region space; h becomes local sort cursor.
    for (int b = t; b < NB; b += 256) {
        int c = h[b];
        gb[b] = (c > 0) ? (b * CAP + atomicAdd(&bucket_cursor[b], c)) : 0;
        h[b] = ls[b];
    }
    __syncthreads();
    // Counting sort into LDS.
#pragma unroll
    for (int j = 0; j < BIN_EPT; ++j) {
        int e = base + j * 256 + t;
        if (e < E) {
            int b = d_[j] >> BKT_SHIFT;
            int r = atomicAdd(&h[b], 1);
            sorted[r] = (s_[j] << BKT_SHIFT) | (d_[j] & BKT_MASK);
            bkt[r] = (unsigned short)b;
        }
    }
    __syncthreads();
    // Coalesced write-out.
#pragma unroll
    for (int j = 0; j < BIN_EPT; ++j) {
        int i = j * 256 + t;
        if (i < count) {
            int b = bkt[i];
            binned[gb[b] + (i - ls[b])] = sorted[i];
        }
    }
}

// One block (512 thr) per bucket: stage bucket's edges in LDS, per-node
// degree count, LDS scan -> row_start (capacity-absolute) + cnt + dinv,
// place csr from the LDS copy.
__global__ __launch_bounds__(512) void k_place(
    const int* __restrict__ binned, const int* __restrict__ bucket_cursor,
    int* __restrict__ row_start, int* __restrict__ cnt, float* __restrict__ dinv,
    int* __restrict__ csr, int n, int NB) {
    __shared__ int eLDS[CAP];
    __shared__ int lcnt[128], sc[128];
    const int b = blockIdx.x;
    const int t = threadIdx.x;
    const int lo = b * CAP;
    const int m = bucket_cursor[b];  // final cursor == bucket count
    if (t < 128) lcnt[t] = 0;
    __syncthreads();
    int i = t;
    for (; i + 3 * 512 < m; i += 4 * 512) {
        int v0 = binned[lo + i], v1 = binned[lo + i + 512];
        int v2 = binned[lo + i + 1024], v3 = binned[lo + i + 1536];
        eLDS[i] = v0; eLDS[i + 512] = v1;
        eLDS[i + 1024] = v2; eLDS[i + 1536] = v3;
        atomicAdd(&lcnt[v0 & BKT_MASK], 1);
        atomicAdd(&lcnt[v1 & BKT_MASK], 1);
        atomicAdd(&lcnt[v2 & BKT_MASK], 1);
        atomicAdd(&lcnt[v3 & BKT_MASK], 1);
    }
    for (; i < m; i += 512) {
        int v = binned[lo + i];
        eLDS[i] = v;
        atomicAdd(&lcnt[v & BKT_MASK], 1);
    }
    __syncthreads();
    int c = 0;
    if (t < 128) { c = lcnt[t]; sc[t] = c; }
    __syncthreads();
    for (int off = 1; off < 128; off <<= 1) {
        int u = 0;
        if (t < 128 && t >= off) u = sc[t - off];
        __syncthreads();
        if (t < 128) sc[t] += u;
        __syncthreads();
    }
    if (t < 128) {
        int excl = sc[t] - c;
        const int node = (b << BKT_SHIFT) + t;
        if (node < n) {
            row_start[node] = lo + excl;
            cnt[node] = c;
            dinv[node] = rsqrtf((float)c + 1.0f);
        }
        lcnt[t] = excl;  // becomes the local cursor
    }
    __syncthreads();
    i = t;
    for (; i + 3 * 512 < m; i += 4 * 512) {
        int v0 = eLDS[i], v1 = eLDS[i + 512];
        int v2 = eLDS[i + 1024], v3 = eLDS[i + 1536];
        int r0 = atomicAdd(&lcnt[v0 & BKT_MASK], 1); csr[lo + r0] = v0 >> BKT_SHIFT;
        int r1 = atomicAdd(&lcnt[v1 & BKT_MASK], 1); csr[lo + r1] = v1 >> BKT_SHIFT;
        int r2 = atomicAdd(&lcnt[v2 & BKT_MASK], 1); csr[lo + r2] = v2 >> BKT_SHIFT;
        int r3 = atomicAdd(&lcnt[v3 & BKT_MASK], 1); csr[lo + r3] = v3 >> BKT_SHIFT;
    }
    for (; i < m; i += 512) {
        int v = eLDS[i];
        int r = atomicAdd(&lcnt[v & BKT_MASK], 1);
        csr[lo + r] = v >> BKT_SHIFT;
    }
}

// g1[row][o] = (x[row] @ W1)[o] * dinv[row]
// W1 staged in LDS, o-major with XOR swizzle; G1R=2 rows per wave per
// iteration (live VGPR ~90 -> 4 waves/SIMD naturally), double-buffered x
// prefetch. (256,2) cap 256 -- far above need, no spill possible.
#define G1R 2
__global__ __launch_bounds__(256, 2) void k_gemm1(
    const float* __restrict__ x, const float* __restrict__ W1,
    const float* __restrict__ dinv, float* __restrict__ g1, int n) {
    __shared__ float wlds[16 * 512];
    const int t = threadIdx.x;
    for (int i = t; i < 8192; i += 256) {
        int k = i >> 4, o = i & 15;
        wlds[o * 512 + (k ^ ((o & 7) << 2))] = W1[i];
    }
    __syncthreads();

    const int lane = t & 63;
    const int wid  = blockIdx.x * 4 + (t >> 6);
    const int nw   = gridDim.x * 4;
    const float4* __restrict__ xv = (const float4*)x;

    int r0 = wid * G1R;
    float4 a[G1R], b[G1R];
#pragma unroll
    for (int r = 0; r < G1R; ++r) {
        a[r] = make_float4(0.f, 0.f, 0.f, 0.f);
        b[r] = a[r];
        if (r0 + r < n) {
            a[r] = xv[(size_t)(r0 + r) * 128 + lane];
            b[r] = xv[(size_t)(r0 + r) * 128 + 64 + lane];
        }
    }

    while (r0 < n) {
        const int r1 = r0 + nw * G1R;
        float4 a2[G1R], b2[G1R];
#pragma unroll
        for (int r = 0; r < G1R; ++r) {
            a2[r] = make_float4(0.f, 0.f, 0.f, 0.f);
            b2[r] = a2[r];
            if (r1 + r < n) {
                a2[r] = xv[(size_t)(r1 + r) * 128 + lane];
                b2[r] = xv[(size_t)(r1 + r) * 128 + 64 + lane];
            }
        }

        float acc[G1R][16];
#pragma unroll
        for (int r = 0; r < G1R; ++r)
#pragma unroll
            for (int o = 0; o < 16; ++o) acc[r][o] = 0.f;

#pragma unroll
        for (int o = 0; o < 16; ++o) {
            const int lp = lane ^ (o & 7);
            float4 wa = *(const float4*)&wlds[o * 512 + 4 * lp];
            float4 wb = *(const float4*)&wlds[o * 512 + 256 + 4 * lp];
#pragma unroll
            for (int r = 0; r < G1R; ++r) {
                float s = fmaf(a[r].x, wa.x, acc[r][o]);
                s = fmaf(a[r].y, wa.y, s);
                s = fmaf(a[r].z, wa.z, s);
                s = fmaf(a[r].w, wa.w, s);
                s = fmaf(b[r].x, wb.x, s);
                s = fmaf(b[r].y, wb.y, s);
                s = fmaf(b[r].z, wb.z, s);
                acc[r][o] = fmaf(b[r].w, wb.w, s);
            }
        }
#pragma unroll
        for (int r = 0; r < G1R; ++r) {
            if (r0 + r >= n) break;
#pragma unroll
            for (int i = 0; i < 8; ++i) {
                float send = (lane & 32) ? acc[r][i] : acc[r][i + 8];
                float recv = __shfl_xor(send, 32);
                float keep = (lane & 32) ? acc[r][i + 8] : acc[r][i];
                acc[r][i] = keep + recv;
            }
#pragma unroll
            for (int i = 0; i < 4; ++i) {
                float send = (lane & 16) ? acc[r][i] : acc[r][i + 4];
                float recv = __shfl_xor(send, 16);
                float keep = (lane & 16) ? acc[r][i + 4] : acc[r][i];
                acc[r][i] = keep + recv;
            }
#pragma unroll
            for (int i = 0; i < 2; ++i) {
                float send = (lane & 8) ? acc[r][i] : acc[r][i + 2];
                float recv = __shfl_xor(send, 8);
                float keep = (lane & 8) ? acc[r][i + 2] : acc[r][i];
                acc[r][i] = keep + recv;
            }
            {
                float send = (lane & 4) ? acc[r][0] : acc[r][1];
                float recv = __shfl_xor(send, 4);
                float keep = (lane & 4) ? acc[r][1] : acc[r][0];
                acc[r][0] = keep + recv;
            }
            float v = acc[r][0];
            v += __shfl_xor(v, 1);
            v += __shfl_xor(v, 2);
            if ((lane & 3) == 0)
                g1[(size_t)(r0 + r) * 16 + (lane >> 2)] = v * dinv[r0 + r];
        }
        r0 = r1;
#pragma unroll
        for (int r = 0; r < G1R; ++r) { a[r] = a2[r]; b[r] = b2[r]; }
    }
}

// Wave per node, FLOAT4 gather: lane = eo*4 + q (16 edge slots x 4 feature
// quads). Fused h2=relu(dinv*(acc+self)+b1), h3=h2@W2, g2=h3*dinv.
__global__ __launch_bounds__(256) void k_gather1(
    const int* __restrict__ row_start, const int* __restrict__ cnt,
    const int* __restrict__ csr, const float* __restrict__ g1,
    const float* __restrict__ dinv, const float* __restrict__ W2,
    const float* __restrict__ b1, float* __restrict__ g2, int n) {
    const int wid = blockIdx.x * 4 + (threadIdx.x >> 6);
    if (wid >= n) return;
    const int lane = threadIdx.x & 63;
    const int q = lane & 3;        // feature quad (4 floats)
    const int eo = lane >> 2;      // 16 edge slots
    const int base = row_start[wid];
    const int deg = cnt[wid];
    float4 acc = make_float4(0.f, 0.f, 0.f, 0.f);
    int j = eo;
    for (; j + 16 < deg; j += 32) {
        int s0 = csr[base + j];
        int s1 = csr[base + j + 16];
        float4 v0 = *(const float4*)&g1[(size_t)s0 * 16 + 4 * q];
        float4 v1 = *(const float4*)&g1[(size_t)s1 * 16 + 4 * q];
        acc.x += v0.x + v1.x;
        acc.y += v0.y + v1.y;
        acc.z += v0.z + v1.z;
        acc.w += v0.w + v1.w;
    }
    for (; j < deg; j += 16) {
        int s = csr[base + j];
        float4 v = *(const float4*)&g1[(size_t)s * 16 + 4 * q];
        acc.x += v.x; acc.y += v.y; acc.z += v.z; acc.w += v.w;
    }
#pragma unroll
    for (int m = 4; m < 64; m <<= 1) {
        acc.x += __shfl_xor(acc.x, m);
        acc.y += __shfl_xor(acc.y, m);
        acc.z += __shfl_xor(acc.z, m);
        acc.w += __shfl_xor(acc.w, m);
    }
    const float dv = dinv[wid];
    float4 self = *(const float4*)&g1[(size_t)wid * 16 + 4 * q];
    float4 bb = *(const float4*)&b1[4 * q];
    float h0 = fmaxf(fmaf(dv, acc.x + self.x, bb.x), 0.f);
    float h1 = fmaxf(fmaf(dv, acc.y + self.y, bb.y), 0.f);
    float h2 = fmaxf(fmaf(dv, acc.z + self.z, bb.z), 0.f);
    float h3 = fmaxf(fmaf(dv, acc.w + self.w, bb.w), 0.f);
    float4 w0 = *(const float4*)&W2[8 * q];      // r0c0 r0c1 r1c0 r1c1
    float4 w1 = *(const float4*)&W2[8 * q + 4];  // r2c0 r2c1 r3c0 r3c1
    float c0 = h0 * w0.x + h1 * w0.z + h2 * w1.x + h3 * w1.z;
    float c1 = h0 * w0.y + h1 * w0.w + h2 * w1.y + h3 * w1.w;
    c0 += __shfl_xor(c0, 1); c0 += __shfl_xor(c0, 2);
    c1 += __shfl_xor(c1, 1); c1 += __shfl_xor(c1, 2);
    if (lane == 0) ((float2*)g2)[wid] = make_float2(c0 * dv, c1 * dv);
}

// Half-wave per node (deg~33: full wave left half the lanes idle).
// Lanes 0-31 -> node 2*wv, lanes 32-63 -> node 2*wv+1; shfl_xor masks
// 1..16 stay within each half. Fuse bias -> out.
__global__ __launch_bounds__(256) void k_gather2(
    const int* __restrict__ row_start, const int* __restrict__ cnt,
    const int* __restrict__ csr, const float* __restrict__ g2,
    const float* __restrict__ dinv, const float* __restrict__ b2,
    float* __restrict__ out, int n) {
    const int wv = blockIdx.x * 4 + (threadIdx.x >> 6);
    const int lane = threadIdx.x & 63;
    const int half = lane >> 5;           // 0 or 1
    const int hl = lane & 31;             // lane within half
    const int wid = 2 * wv + half;
    if (wid >= n) return;
    const int base = row_start[wid];
    const int deg = cnt[wid];
    float a0 = 0.f, a1 = 0.f;
    for (int j = hl; j < deg; j += 32) {
        int s = csr[base + j];
        float2 v = ((const float2*)g2)[s];
        a0 += v.x; a1 += v.y;
    }
#pragma unroll
    for (int m = 1; m < 32; m <<= 1) {
        a0 += __shfl_xor(a0, m);
        a1 += __shfl_xor(a1, m);
    }
    if (hl == 0) {
        float dv = dinv[wid];
        float2 g = ((const float2*)g2)[wid];
        ((float2*)out)[wid] = make_float2(fmaf(dv, a0 + g.x, b2[0]),
                                          fmaf(dv, a1 + g.y, b2[1]));
    }
}

extern "C" void kernel_launch(void* const* d_in, const int* in_sizes, int n_in,
                              void* d_out, int out_size, void* d_ws, size_t ws_size,
                              hipStream_t stream) {
    const float* x  = (const float*)d_in[0];
    const int*   ei = (const int*)d_in[1];
    const float* W1 = (const float*)d_in[2];
    const float* b1 = (const float*)d_in[3];
    const float* W2 = (const float*)d_in[4];
    const float* b2 = (const float*)d_in[5];
    float* out = (float*)d_out;

    const int n = in_sizes[0] / 512;
    const int E = in_sizes[1] / 2;
    const int* src = ei;
    const int* dst = ei + E;

    const int NB = (n + (1 << BKT_SHIFT) - 1) >> BKT_SHIFT;      // buckets (<=784)
    const int nb_bin = (E + 256 * BIN_EPT - 1) / (256 * BIN_EPT); // bin blocks

    char* ws = (char*)d_ws;
    size_t off = 0;
    auto alloc = [&](size_t bytes) {
        char* p = ws + off;
        off += (bytes + 255) & ~(size_t)255;
        return p;
    };
    float* dinv      = (float*)alloc((size_t)n * 4);
    float* g1        = (float*)alloc((size_t)n * 16 * 4);
    float* g2        = (float*)alloc((size_t)n * 2 * 4);
    int*   row_start = (int*)alloc((size_t)n * 4);
    int*   cnt       = (int*)alloc((size_t)n * 4);
    int*   csr       = (int*)alloc((size_t)NB * CAP * 4);
    int*   binned    = (int*)alloc((size_t)NB * CAP * 4);
    int*   bucket_cursor = (int*)alloc((size_t)NB * 4);

    hipMemsetAsync(bucket_cursor, 0, (size_t)NB * 4, stream);

    const int nb_w  = (n + 3) / 4;   // wave-per-node kernels, 4 waves/block
    const int nb_w2 = (n + 7) / 8;   // half-wave-per-node, 8 nodes/block

    // k_bin dynamic LDS: h/ls/gb (3*NB ints) + sorted (4096 ints) + bkt (4096 u16)
    const int bin_lds = 3 * NB * 4 + 256 * BIN_EPT * 4 + 256 * BIN_EPT * 2;

    k_bin<<<nb_bin, 256, bin_lds, stream>>>(src, dst, bucket_cursor, binned, E, NB);
    k_place<<<NB, 512, 0, stream>>>(binned, bucket_cursor, row_start, cnt, dinv, csr, n, NB);
    k_gemm1<<<2048, 256, 0, stream>>>(x, W1, dinv, g1, n);
    k_gather1<<<nb_w, 256, 0, stream>>>(row_start, cnt, csr, g1, dinv, W2, b1, g2, n);
    k_gather2<<<nb_w2, 256, 0, stream>>>(row_start, cnt, csr, g2, dinv, b2, out, n);
}

// Round 21
// 184.317 us; speedup vs baseline: 1.0305x; 1.0305x over previous
//
#include <hip/hip_runtime.h>

// GCN 2-layer forward, CSR-gather formulation. All fp32.
// out[d] = dinv[d] * ( sum_{e: src->d} g[src] + g[d] ) + bias,
// where g[i] = (h W)[i] * dinv[i]; self-loop is the +g[d] term.
// CSR built via SINGLE-PASS capacity binning, 782 buckets x 128 nodes:
//   k_bin:    stage edges in regs, LDS hist+scan (4 slots/thread), one
//             global reserve per (block,bucket), LDS counting sort,
//             COALESCED write of packed (src<<7|dst&127) runs into b*CAP+...
//   k_place:  per-bucket (512 thr): bucket's edges staged in LDS once;
//             per-node counts/scan in LDS -> row_start/cnt/dinv; place csr
//             from the LDS copy.
//   k_gemm1:  g1 = (x @ W1) * dinv. W1 in LDS (o-major XOR-swizzled);
//             G1R=4 rows/wave/iter, double-buffered x prefetch, (256,2).
//             REGISTER RULE (r14/r18/r20 post-mortems): ~150 live VGPRs;
//             (256,2) is the only non-spilling bound; G1R=2 for higher
//             occupancy was flat (r20) -> kernel is at its L3/HBM x-read
//             equilibrium, NOT occupancy-limited. DO NOT TIGHTEN.
//   k_gather1: CSR gather of g1, float4-vectorized, HALF-WAVE per node
//             (2 nodes/wave; 8 edge slots x 4 quads per half -- deg~33
//             made full-wave 16-slot tails ~94% idle).
//   k_gather2: CSR gather of g2, half-wave per node (deg~33); bias -> out.

#define BKT_SHIFT 7            // 128 nodes per bucket
#define BKT_MASK 127
#define BIN_EPT 16             // edges per thread in k_bin (4096/block)
#define CAP 5120               // per-bucket capacity (expected 4092, sigma~64)

// Bin packed edges (src<<7 | dst&127) into per-bucket capacity regions.
// LDS counting sort inside the block -> coalesced run writes.
// Dynamic LDS: h[NB], ls[NB], gb[NB], sorted[4096] int, bkt[4096] ushort.
__global__ __launch_bounds__(256) void k_bin(
    const int* __restrict__ src, const int* __restrict__ dst,
    int* __restrict__ bucket_cursor, int* __restrict__ binned, int E, int NB) {
    extern __shared__ int lds[];
    int* h  = lds;
    int* ls = lds + NB;
    int* gb = lds + 2 * NB;
    int* sorted = lds + 3 * NB;
    unsigned short* bkt = (unsigned short*)(sorted + 256 * BIN_EPT);
    __shared__ int ps[256];
    const int t = threadIdx.x;
    const int base = blockIdx.x * (256 * BIN_EPT);
    const int count = min(256 * BIN_EPT, E - base);  // valid edges this block

    for (int b = t; b < NB; b += 256) h[b] = 0;
    __syncthreads();
    // Stage edges in registers + local histogram.
    int s_[BIN_EPT], d_[BIN_EPT];
#pragma unroll
    for (int j = 0; j < BIN_EPT; ++j) {
        int e = base + j * 256 + t;
        if (e < E) {
            s_[j] = src[e];
            d_[j] = dst[e];
            atomicAdd(&h[d_[j] >> BKT_SHIFT], 1);
        }
    }
    __syncthreads();
    // Block scan of h (4 slots per thread): serial partial + 256-scan.
    {
        int v0 = 0, v1 = 0, v2 = 0, v3 = 0;
        int i0 = 4 * t;
        if (i0 + 0 < NB) v0 = h[i0 + 0];
        if (i0 + 1 < NB) v1 = h[i0 + 1];
        if (i0 + 2 < NB) v2 = h[i0 + 2];
        if (i0 + 3 < NB) v3 = h[i0 + 3];
        int tot = v0 + v1 + v2 + v3;
        ps[t] = tot;
        __syncthreads();
        for (int off = 1; off < 256; off <<= 1) {
            int u = (t >= off) ? ps[t - off] : 0;
            __syncthreads();
            ps[t] += u;
            __syncthreads();
        }
        int excl = ps[t] - tot;
        if (i0 + 0 < NB) { ls[i0 + 0] = excl; excl += v0; }
        if (i0 + 1 < NB) { ls[i0 + 1] = excl; excl += v1; }
        if (i0 + 2 < NB) { ls[i0 + 2] = excl; excl += v2; }
        if (i0 + 3 < NB) { ls[i0 + 3] = excl; }
    }
    __syncthreads();
    // Reserve capacity-region space; h becomes local sort cursor.
    for (int b = t; b < NB; b += 256) {
        int c = h[b];
        gb[b] = (c > 0) ? (b * CAP + atomicAdd(&bucket_cursor[b], c)) : 0;
        h[b] = ls[b];
    }
    __syncthreads();
    // Counting sort into LDS.
#pragma unroll
    for (int j = 0; j < BIN_EPT; ++j) {
        int e = base + j * 256 + t;
        if (e < E) {
            int b = d_[j] >> BKT_SHIFT;
            int r = atomicAdd(&h[b], 1);
            sorted[r] = (s_[j] << BKT_SHIFT) | (d_[j] & BKT_MASK);
            bkt[r] = (unsigned short)b;
        }
    }
    __syncthreads();
    // Coalesced write-out.
#pragma unroll
    for (int j = 0; j < BIN_EPT; ++j) {
        int i = j * 256 + t;
        if (i < count) {
            int b = bkt[i];
            binned[gb[b] + (i - ls[b])] = sorted[i];
        }
    }
}

// One block (512 thr) per bucket: stage bucket's edges in LDS, per-node
// degree count, LDS scan -> row_start (capacity-absolute) + cnt + dinv,
// place csr from the LDS copy.
__global__ __launch_bounds__(512) void k_place(
    const int* __restrict__ binned, const int* __restrict__ bucket_cursor,
    int* __restrict__ row_start, int* __restrict__ cnt, float* __restrict__ dinv,
    int* __restrict__ csr, int n, int NB) {
    __shared__ int eLDS[CAP];
    __shared__ int lcnt[128], sc[128];
    const int b = blockIdx.x;
    const int t = threadIdx.x;
    const int lo = b * CAP;
    const int m = bucket_cursor[b];  // final cursor == bucket count
    if (t < 128) lcnt[t] = 0;
    __syncthreads();
    int i = t;
    for (; i + 3 * 512 < m; i += 4 * 512) {
        int v0 = binned[lo + i], v1 = binned[lo + i + 512];
        int v2 = binned[lo + i + 1024], v3 = binned[lo + i + 1536];
        eLDS[i] = v0; eLDS[i + 512] = v1;
        eLDS[i + 1024] = v2; eLDS[i + 1536] = v3;
        atomicAdd(&lcnt[v0 & BKT_MASK], 1);
        atomicAdd(&lcnt[v1 & BKT_MASK], 1);
        atomicAdd(&lcnt[v2 & BKT_MASK], 1);
        atomicAdd(&lcnt[v3 & BKT_MASK], 1);
    }
    for (; i < m; i += 512) {
        int v = binned[lo + i];
        eLDS[i] = v;
        atomicAdd(&lcnt[v & BKT_MASK], 1);
    }
    __syncthreads();
    int c = 0;
    if (t < 128) { c = lcnt[t]; sc[t] = c; }
    __syncthreads();
    for (int off = 1; off < 128; off <<= 1) {
        int u = 0;
        if (t < 128 && t >= off) u = sc[t - off];
        __syncthreads();
        if (t < 128) sc[t] += u;
        __syncthreads();
    }
    if (t < 128) {
        int excl = sc[t] - c;
        const int node = (b << BKT_SHIFT) + t;
        if (node < n) {
            row_start[node] = lo + excl;
            cnt[node] = c;
            dinv[node] = rsqrtf((float)c + 1.0f);
        }
        lcnt[t] = excl;  // becomes the local cursor
    }
    __syncthreads();
    i = t;
    for (; i + 3 * 512 < m; i += 4 * 512) {
        int v0 = eLDS[i], v1 = eLDS[i + 512];
        int v2 = eLDS[i + 1024], v3 = eLDS[i + 1536];
        int r0 = atomicAdd(&lcnt[v0 & BKT_MASK], 1); csr[lo + r0] = v0 >> BKT_SHIFT;
        int r1 = atomicAdd(&lcnt[v1 & BKT_MASK], 1); csr[lo + r1] = v1 >> BKT_SHIFT;
        int r2 = atomicAdd(&lcnt[v2 & BKT_MASK], 1); csr[lo + r2] = v2 >> BKT_SHIFT;
        int r3 = atomicAdd(&lcnt[v3 & BKT_MASK], 1); csr[lo + r3] = v3 >> BKT_SHIFT;
    }
    for (; i < m; i += 512) {
        int v = eLDS[i];
        int r = atomicAdd(&lcnt[v & BKT_MASK], 1);
        csr[lo + r] = v >> BKT_SHIFT;
    }
}

// g1[row][o] = (x[row] @ W1)[o] * dinv[row]
// W1 staged in LDS, o-major with XOR swizzle; 4 rows per wave per iteration,
// double-buffered x prefetch. (256,2): ~150 VGPR live, no spill. DO NOT
// TIGHTEN THE LAUNCH BOUND (see header).
#define G1R 4
__global__ __launch_bounds__(256, 2) void k_gemm1(
    const float* __restrict__ x, const float* __restrict__ W1,
    const float* __restrict__ dinv, float* __restrict__ g1, int n) {
    __shared__ float wlds[16 * 512];
    const int t = threadIdx.x;
    for (int i = t; i < 8192; i += 256) {
        int k = i >> 4, o = i & 15;
        wlds[o * 512 + (k ^ ((o & 7) << 2))] = W1[i];
    }
    __syncthreads();

    const int lane = t & 63;
    const int wid  = blockIdx.x * 4 + (t >> 6);
    const int nw   = gridDim.x * 4;
    const float4* __restrict__ xv = (const float4*)x;

    int r0 = wid * G1R;
    float4 a[G1R], b[G1R];
#pragma unroll
    for (int r = 0; r < G1R; ++r) {
        a[r] = make_float4(0.f, 0.f, 0.f, 0.f);
        b[r] = a[r];
        if (r0 + r < n) {
            a[r] = xv[(size_t)(r0 + r) * 128 + lane];
            b[r] = xv[(size_t)(r0 + r) * 128 + 64 + lane];
        }
    }

    while (r0 < n) {
        const int r1 = r0 + nw * G1R;
        float4 a2[G1R], b2[G1R];
#pragma unroll
        for (int r = 0; r < G1R; ++r) {
            a2[r] = make_float4(0.f, 0.f, 0.f, 0.f);
            b2[r] = a2[r];
            if (r1 + r < n) {
                a2[r] = xv[(size_t)(r1 + r) * 128 + lane];
                b2[r] = xv[(size_t)(r1 + r) * 128 + 64 + lane];
            }
        }

        float acc[G1R][16];
#pragma unroll
        for (int r = 0; r < G1R; ++r)
#pragma unroll
            for (int o = 0; o < 16; ++o) acc[r][o] = 0.f;

#pragma unroll
        for (int o = 0; o < 16; ++o) {
            const int lp = lane ^ (o & 7);
            float4 wa = *(const float4*)&wlds[o * 512 + 4 * lp];
            float4 wb = *(const float4*)&wlds[o * 512 + 256 + 4 * lp];
#pragma unroll
            for (int r = 0; r < G1R; ++r) {
                float s = fmaf(a[r].x, wa.x, acc[r][o]);
                s = fmaf(a[r].y, wa.y, s);
                s = fmaf(a[r].z, wa.z, s);
                s = fmaf(a[r].w, wa.w, s);
                s = fmaf(b[r].x, wb.x, s);
                s = fmaf(b[r].y, wb.y, s);
                s = fmaf(b[r].z, wb.z, s);
                acc[r][o] = fmaf(b[r].w, wb.w, s);
            }
        }
#pragma unroll
        for (int r = 0; r < G1R; ++r) {
            if (r0 + r >= n) break;
#pragma unroll
            for (int i = 0; i < 8; ++i) {
                float send = (lane & 32) ? acc[r][i] : acc[r][i + 8];
                float recv = __shfl_xor(send, 32);
                float keep = (lane & 32) ? acc[r][i + 8] : acc[r][i];
                acc[r][i] = keep + recv;
            }
#pragma unroll
            for (int i = 0; i < 4; ++i) {
                float send = (lane & 16) ? acc[r][i] : acc[r][i + 4];
                float recv = __shfl_xor(send, 16);
                float keep = (lane & 16) ? acc[r][i + 4] : acc[r][i];
                acc[r][i] = keep + recv;
            }
#pragma unroll
            for (int i = 0; i < 2; ++i) {
                float send = (lane & 8) ? acc[r][i] : acc[r][i + 2];
                float recv = __shfl_xor(send, 8);
                float keep = (lane & 8) ? acc[r][i + 2] : acc[r][i];
                acc[r][i] = keep + recv;
            }
            {
                float send = (lane & 4) ? acc[r][0] : acc[r][1];
                float recv = __shfl_xor(send, 4);
                float keep = (lane & 4) ? acc[r][1] : acc[r][0];
                acc[r][0] = keep + recv;
            }
            float v = acc[r][0];
            v += __shfl_xor(v, 1);
            v += __shfl_xor(v, 2);
            if ((lane & 3) == 0)
                g1[(size_t)(r0 + r) * 16 + (lane >> 2)] = v * dinv[r0 + r];
        }
        r0 = r1;
#pragma unroll
        for (int r = 0; r < G1R; ++r) { a[r] = a2[r]; b[r] = b2[r]; }
    }
}

// HALF-WAVE per node, float4 gather: hl = eo*4 + q within each 32-lane half
// (8 edge slots x 4 feature quads); 2 nodes per wave. deg~33: 16-slot
// full-wave tails were ~94% idle. All shfl_xor masks < 32 stay in-half.
// Fused h2=relu(dinv*(acc+self)+b1), h3=h2@W2, g2=h3*dinv.
__global__ __launch_bounds__(256) void k_gather1(
    const int* __restrict__ row_start, const int* __restrict__ cnt,
    const int* __restrict__ csr, const float* __restrict__ g1,
    const float* __restrict__ dinv, const float* __restrict__ W2,
    const float* __restrict__ b1, float* __restrict__ g2, int n) {
    const int wv = blockIdx.x * 4 + (threadIdx.x >> 6);
    const int lane = threadIdx.x & 63;
    const int half = lane >> 5;
    const int hl = lane & 31;
    const int wid = 2 * wv + half;
    if (wid >= n) return;
    const int q = hl & 3;          // feature quad (4 floats)
    const int eo = hl >> 2;        // 8 edge slots
    const int base = row_start[wid];
    const int deg = cnt[wid];
    float4 acc = make_float4(0.f, 0.f, 0.f, 0.f);
    int j = eo;
    // 2-way unroll: 16 edges in flight per node (32 per wave).
    for (; j + 8 < deg; j += 16) {
        int s0 = csr[base + j];
        int s1 = csr[base + j + 8];
        float4 v0 = *(const float4*)&g1[(size_t)s0 * 16 + 4 * q];
        float4 v1 = *(const float4*)&g1[(size_t)s1 * 16 + 4 * q];
        acc.x += v0.x + v1.x;
        acc.y += v0.y + v1.y;
        acc.z += v0.z + v1.z;
        acc.w += v0.w + v1.w;
    }
    for (; j < deg; j += 8) {
        int s = csr[base + j];
        float4 v = *(const float4*)&g1[(size_t)s * 16 + 4 * q];
        acc.x += v.x; acc.y += v.y; acc.z += v.z; acc.w += v.w;
    }
    // Reduce over the 8 edge slots (lane bits 2..4 within the half).
#pragma unroll
    for (int m = 4; m < 32; m <<= 1) {
        acc.x += __shfl_xor(acc.x, m);
        acc.y += __shfl_xor(acc.y, m);
        acc.z += __shfl_xor(acc.z, m);
        acc.w += __shfl_xor(acc.w, m);
    }
    const float dv = dinv[wid];
    float4 self = *(const float4*)&g1[(size_t)wid * 16 + 4 * q];
    float4 bb = *(const float4*)&b1[4 * q];
    float h0 = fmaxf(fmaf(dv, acc.x + self.x, bb.x), 0.f);
    float h1 = fmaxf(fmaf(dv, acc.y + self.y, bb.y), 0.f);
    float h2 = fmaxf(fmaf(dv, acc.z + self.z, bb.z), 0.f);
    float h3 = fmaxf(fmaf(dv, acc.w + self.w, bb.w), 0.f);
    float4 w0 = *(const float4*)&W2[8 * q];      // r0c0 r0c1 r1c0 r1c1
    float4 w1 = *(const float4*)&W2[8 * q + 4];  // r2c0 r2c1 r3c0 r3c1
    float c0 = h0 * w0.x + h1 * w0.z + h2 * w1.x + h3 * w1.z;
    float c1 = h0 * w0.y + h1 * w0.w + h2 * w1.y + h3 * w1.w;
    // Reduce over the 4 feature quads (lane bits 0..1).
    c0 += __shfl_xor(c0, 1); c0 += __shfl_xor(c0, 2);
    c1 += __shfl_xor(c1, 1); c1 += __shfl_xor(c1, 2);
    if (hl == 0) ((float2*)g2)[wid] = make_float2(c0 * dv, c1 * dv);
}

// Half-wave per node (deg~33). Lanes 0-31 -> node 2*wv, lanes 32-63 ->
// node 2*wv+1; shfl_xor masks 1..16 stay within each half. Bias -> out.
__global__ __launch_bounds__(256) void k_gather2(
    const int* __restrict__ row_start, const int* __restrict__ cnt,
    const int* __restrict__ csr, const float* __restrict__ g2,
    const float* __restrict__ dinv, const float* __restrict__ b2,
    float* __restrict__ out, int n) {
    const int wv = blockIdx.x * 4 + (threadIdx.x >> 6);
    const int lane = threadIdx.x & 63;
    const int half = lane >> 5;           // 0 or 1
    const int hl = lane & 31;             // lane within half
    const int wid = 2 * wv + half;
    if (wid >= n) return;
    const int base = row_start[wid];
    const int deg = cnt[wid];
    float a0 = 0.f, a1 = 0.f;
    for (int j = hl; j < deg; j += 32) {
        int s = csr[base + j];
        float2 v = ((const float2*)g2)[s];
        a0 += v.x; a1 += v.y;
    }
#pragma unroll
    for (int m = 1; m < 32; m <<= 1) {
        a0 += __shfl_xor(a0, m);
        a1 += __shfl_xor(a1, m);
    }
    if (hl == 0) {
        float dv = dinv[wid];
        float2 g = ((const float2*)g2)[wid];
        ((float2*)out)[wid] = make_float2(fmaf(dv, a0 + g.x, b2[0]),
                                          fmaf(dv, a1 + g.y, b2[1]));
    }
}

extern "C" void kernel_launch(void* const* d_in, const int* in_sizes, int n_in,
                              void* d_out, int out_size, void* d_ws, size_t ws_size,
                              hipStream_t stream) {
    const float* x  = (const float*)d_in[0];
    const int*   ei = (const int*)d_in[1];
    const float* W1 = (const float*)d_in[2];
    const float* b1 = (const float*)d_in[3];
    const float* W2 = (const float*)d_in[4];
    const float* b2 = (const float*)d_in[5];
    float* out = (float*)d_out;

    const int n = in_sizes[0] / 512;
    const int E = in_sizes[1] / 2;
    const int* src = ei;
    const int* dst = ei + E;

    const int NB = (n + (1 << BKT_SHIFT) - 1) >> BKT_SHIFT;      // buckets (<=784)
    const int nb_bin = (E + 256 * BIN_EPT - 1) / (256 * BIN_EPT); // bin blocks

    char* ws = (char*)d_ws;
    size_t off = 0;
    auto alloc = [&](size_t bytes) {
        char* p = ws + off;
        off += (bytes + 255) & ~(size_t)255;
        return p;
    };
    float* dinv      = (float*)alloc((size_t)n * 4);
    float* g1        = (float*)alloc((size_t)n * 16 * 4);
    float* g2        = (float*)alloc((size_t)n * 2 * 4);
    int*   row_start = (int*)alloc((size_t)n * 4);
    int*   cnt       = (int*)alloc((size_t)n * 4);
    int*   csr       = (int*)alloc((size_t)NB * CAP * 4);
    int*   binned    = (int*)alloc((size_t)NB * CAP * 4);
    int*   bucket_cursor = (int*)alloc((size_t)NB * 4);

    hipMemsetAsync(bucket_cursor, 0, (size_t)NB * 4, stream);

    const int nb_w2 = (n + 7) / 8;   // half-wave-per-node, 8 nodes/block

    // k_bin dynamic LDS: h/ls/gb (3*NB ints) + sorted (4096 ints) + bkt (4096 u16)
    const int bin_lds = 3 * NB * 4 + 256 * BIN_EPT * 4 + 256 * BIN_EPT * 2;

    k_bin<<<nb_bin, 256, bin_lds, stream>>>(src, dst, bucket_cursor, binned, E, NB);
    k_place<<<NB, 512, 0, stream>>>(binned, bucket_cursor, row_start, cnt, dinv, csr, n, NB);
    k_gemm1<<<1024, 256, 0, stream>>>(x, W1, dinv, g1, n);
    k_gather1<<<nb_w2, 256, 0, stream>>>(row_start, cnt, csr, g1, dinv, W2, b1, g2, n);
    k_gather2<<<nb_w2, 256, 0, stream>>>(row_start, cnt, csr, g2, dinv, b2, out, n);
}